// Round 1
// baseline (265.617 us; speedup 1.0000x reference)
//
#include <hip/hip_runtime.h>
#include <hip/hip_fp16.h>
#include <math.h>

// clDice loss on 32x1x512x512: sigmoid + dice + 10x soft-skeletonize + skel dice.
// R1: per-block partials (1059 -> 466 us). R3: fused 2 iters/kernel via LDS (485).
// R5: 256 thr/block (316). R7: fp16 global ping-pong + fp16-packed LDS B (262).
// R9: PACKED fp16 stencil math (v_pk_min/max/fma_f16, 2 px/instr) + fp16 LDS A:
//     LDS 34.3K -> 22.2K => 7 blocks/CU (28 waves, was 16); LDS read bytes halved;
//     dice partials fused into fillA (fp32 pre-pack values, same numerics as R7);
//     min/max chain exact (monotone rounding commutes); only the skel update gains
//     ~1 fp16 rounding/iter (non-amplifying, |d(out)/d(in)| <= 1 on all paths).

#define H 512
#define W 512
#define IMG (H * W)
#define NIMG 64
#define NPRED 32

#define APU 40      // A row pitch in uints (2 fp16/uint); uint u <-> gx = tileX-8+2u
#define AROWS 74    // row r <-> gy = tileY + r - 4; real data rows 0..71, u 2..37
#define BP2 38      // B row pitch in uints; uint u <-> tile cols 2u-4, 2u-3
#define BROWS 68    // row br <-> gy = tileY + br - 2

#define PINF2 0x7C007C00u   // +inf,+inf (erosion-neutral pad)
#define NINF2 0xFC00FC00u   // -inf,-inf (dilation-neutral mask)
#define ONE2  0x3C003C00u   // 1.0,1.0

typedef _Float16 f16;
typedef _Float16 h2 __attribute__((ext_vector_type(2)));
typedef __fp16 fp16v2 __attribute__((ext_vector_type(2)));

__device__ __forceinline__ uint pack2(float a, float b) {
    fp16v2 h = __builtin_amdgcn_cvt_pkrtz(a, b);
    return __builtin_bit_cast(uint, h);
}

__device__ __forceinline__ uint pmin(uint a, uint b) {
    uint d; asm("v_pk_min_f16 %0, %1, %2" : "=v"(d) : "v"(a), "v"(b)); return d;
}
__device__ __forceinline__ uint pmax(uint a, uint b) {
    uint d; asm("v_pk_max_f16 %0, %1, %2" : "=v"(d) : "v"(a), "v"(b)); return d;
}
// (hi<<16)|(lo>>16): builds the odd-aligned fp16 pair from two even-aligned pairs
__device__ __forceinline__ uint abit(uint hi, uint lo) {
    return __builtin_amdgcn_alignbit(hi, lo, 16);
}

__device__ __forceinline__ float wsum64(float v) {
#pragma unroll
    for (int o = 32; o > 0; o >>= 1) v += __shfl_down(v, o);
    return v;
}

// Packed horizontal 3-min at 4 aligned pairs (cols base-2 .. base+5) from a row of
// even-aligned fp16 pairs; p points at the uint of col base-4. Also returns the
// center pairs (cols base..base+3) for the skel update.
__device__ __forceinline__ void hmin4p(const uint* __restrict__ p, uint m[4], uint sc[2]) {
    uint2 w0 = *(const uint2*)(p);        // cols base-4..-1
    uint2 w1 = *(const uint2*)(p + 2);    // cols base..+3
    uint2 w2 = *(const uint2*)(p + 4);    // cols base+4..+7
    sc[0] = w1.x; sc[1] = w1.y;
    uint s01 = abit(w0.y, w0.x);          // (base-3, base-2)
    uint s12 = abit(w1.x, w0.y);          // (base-1, base)
    uint s23 = abit(w1.y, w1.x);          // (base+1, base+2)
    uint s34 = abit(w2.x, w1.y);          // (base+3, base+4)
    uint s45 = abit(w2.y, w2.x);          // (base+5, base+6)
    m[0] = pmin(s01, pmin(w0.y, s12));    // pair (base-2, base-1)
    m[1] = pmin(s12, pmin(w1.x, s23));    // pair (base,   base+1)
    m[2] = pmin(s23, pmin(w1.y, s34));    // pair (base+2, base+3)
    m[3] = pmin(s34, pmin(w2.x, s45));    // pair (base+4, base+5)
}

// Vertical 3-min + out-of-image mask (-inf). Row mask uniform per row; column
// masks are pair-uniform because image x-bounds (0,512) are even and pairs are
// even-aligned, so a pair is never split by the boundary.
__device__ __forceinline__ void erodep(const uint a[4], const uint b[4], const uint c[4],
                                       bool rowok, const bool eok[4], uint e[4]) {
#pragma unroll
    for (int i = 0; i < 4; i++) {
        uint v = pmin(a[i], pmin(b[i], c[i]));
        e[i] = (rowok && eok[i]) ? v : NINF2;
    }
}

// Packed horizontal 3-max at the 2 center pairs; ec = eroded center pairs.
__device__ __forceinline__ void hmaxp(const uint e[4], uint hx[2], uint ec[2]) {
    uint a12 = abit(e[1], e[0]);          // (base-1, base)
    uint a23 = abit(e[2], e[1]);          // (base+1, base+2)
    uint a34 = abit(e[3], e[2]);          // (base+3, base+4)
    hx[0] = pmax(a12, pmax(e[1], a23));
    hx[1] = pmax(a23, pmax(e[2], a34));
    ec[0] = e[1]; ec[1] = e[2];
}

// skel update, packed fp16: o = clamp(s - (s-e)*t, 0, 1).
__device__ __forceinline__ uint upd_pair(uint s, uint ec, uint t) {
    h2 sh = __builtin_bit_cast(h2, s);
    h2 eh = __builtin_bit_cast(h2, ec);
    h2 th = __builtin_bit_cast(h2, t);
    h2 o = sh - (sh - eh) * th;           // v_pk_add + v_pk_fma
    return pmin(pmax(__builtin_bit_cast(uint, o), 0u), ONE2);
}

// Fill packed-fp16 LDS A from fp32 source (optional sigmoid); fuse dice partials
// over the 64x64 interior (each interior pixel visited exactly once, in fp32
// BEFORE the fp16 pack -> identical dice numerics to the fp32-LDS version).
template<int SIG>
__device__ float2 fillA_f32p(uint* __restrict__ A, const float* __restrict__ src,
                             const float* __restrict__ tgt,
                             int tileX, int tileY, int tid) {
    float a = 0.0f, b = 0.0f;
    for (int it = tid; it < AROWS * 20; it += 256) {
        int r = it / 20;
        int u2 = it - r * 20;                 // uint2 slot: 4 cols
        int gy = tileY + r - 4;
        int gx = tileX - 8 + 4 * u2;
        uint2 v = make_uint2(PINF2, PINF2);
        if (r < 72 && (unsigned)(u2 - 1) < 18u && (unsigned)gy < (unsigned)H &&
            (unsigned)gx < (unsigned)W) {
            float4 f = *(const float4*)(src + (size_t)gy * W + gx);
            if (SIG) {
                f.x = 1.0f / (1.0f + __expf(-f.x));
                f.y = 1.0f / (1.0f + __expf(-f.y));
                f.z = 1.0f / (1.0f + __expf(-f.z));
                f.w = 1.0f / (1.0f + __expf(-f.w));
            }
            if (((unsigned)(gx - tileX) < 64u) && ((unsigned)(gy - tileY) < 64u)) {
                if (SIG) {
                    float4 t = *(const float4*)(tgt + (size_t)gy * W + gx);
                    a += f.x * t.x + f.y * t.y + f.z * t.z + f.w * t.w;
                    b += f.x + f.y + f.z + f.w;
                } else {
                    a += f.x + f.y + f.z + f.w;
                }
            }
            v.x = pack2(f.x, f.y);
            v.y = pack2(f.z, f.w);
        }
        *(uint2*)(A + r * APU + 2 * u2) = v;
    }
    return make_float2(a, b);
}

__device__ void fillA_f16p(uint* __restrict__ A, const f16* __restrict__ src,
                           int tileX, int tileY, int tid) {
    for (int it = tid; it < AROWS * 20; it += 256) {
        int r = it / 20;
        int u2 = it - r * 20;
        int gy = tileY + r - 4;
        int gx = tileX - 8 + 4 * u2;
        uint2 v = make_uint2(PINF2, PINF2);
        if (r < 72 && (unsigned)(u2 - 1) < 18u && (unsigned)gy < (unsigned)H &&
            (unsigned)gx < (unsigned)W) {
            v = *(const uint2*)(src + (size_t)gy * W + gx);
        }
        *(uint2*)(A + r * APU + 2 * u2) = v;
    }
}

// Stage 1: one skeletonize iteration A(fp16 packed) -> B(fp16 packed).
// 252 items = 14 strips(5 rows) x 18 quads(4 cols); rolling 3-row window.
__device__ void stage1(const uint* __restrict__ Au, uint* __restrict__ Bu,
                       int tileX, int tileY, int tid) {
    for (int item = tid; item < 252; item += 256) {
        const int s = item / 18;
        const int q = item - s * 18;
        const int gcb = tileX - 4 + 4 * q;
        const int ys = tileY - 2 + 5 * s;
        bool eok[4], wok[2];
#pragma unroll
        for (int i = 0; i < 4; i++) eok[i] = ((unsigned)(gcb - 2 + 2 * i) < 511u);
        wok[0] = ((unsigned)gcb < 511u);
        wok[1] = ((unsigned)(gcb + 2) < 511u);
        const int lr = 5 * s + 2;
        const uint* Ab = Au + 2 * q;
        uint m[3][4], sc[3][2], hx[3][2], e[4], ec_cur[2], ec_nxt[2], tsc[2];
        hmin4p(Ab + (lr - 2) * APU, m[0], tsc);
        hmin4p(Ab + (lr - 1) * APU, m[1], tsc);
        hmin4p(Ab + (lr + 0) * APU, m[2], sc[0]);
        erodep(m[0], m[1], m[2], (unsigned)(ys - 1) < (unsigned)H, eok, e);
        hmaxp(e, hx[0], ec_nxt);
        hmin4p(Ab + (lr + 1) * APU, m[0], sc[1]);
        erodep(m[1], m[2], m[0], (unsigned)ys < (unsigned)H, eok, e);
        hmaxp(e, hx[1], ec_cur);
#pragma unroll
        for (int k = 0; k < 5; k++) {
            hmin4p(Ab + (lr + 2 + k) * APU, m[(k + 1) % 3], sc[(2 + k) % 3]);
            erodep(m[(k + 2) % 3], m[k % 3], m[(k + 1) % 3],
                   (unsigned)(ys + k + 1) < (unsigned)H, eok, e);
            hmaxp(e, hx[(k + 2) % 3], ec_nxt);
            int br = 5 * s + k;
            if (br < BROWS) {
                uint t0 = pmax(hx[k % 3][0], pmax(hx[(k + 1) % 3][0], hx[(k + 2) % 3][0]));
                uint t1 = pmax(hx[k % 3][1], pmax(hx[(k + 1) % 3][1], hx[(k + 2) % 3][1]));
                uint o0 = upd_pair(sc[k % 3][0], ec_cur[0], t0);
                uint o1 = upd_pair(sc[k % 3][1], ec_cur[1], t1);
                bool rin = ((unsigned)(ys + k) < (unsigned)H);
                uint2 wv;
                wv.x = (rin && wok[0]) ? o0 : PINF2;
                wv.y = (rin && wok[1]) ? o1 : PINF2;
                *(uint2*)(Bu + br * BP2 + 2 * q) = wv;
            }
            ec_cur[0] = ec_nxt[0]; ec_cur[1] = ec_nxt[1];
        }
    }
}

// Stage 2: second iteration B(fp16) -> interior 64x64 (fp16 global or fp32 regs).
// 256 threads: 16 col-quads x 16 4-row strips.
template<bool TOREG>
__device__ void stage2(const uint* __restrict__ Bu, int tileX, int tileY,
                       int tx, int ty, f16* __restrict__ gdst, float (*oreg)[4]) {
    const int X = tileX + 4 * tx;
    const int gy0 = tileY + 4 * ty;
    const int rb = 4 * ty + 2;
    bool eok[4];
    eok[0] = (X != 0);
    eok[1] = true;
    eok[2] = true;
    eok[3] = (X + 4 < W);
    const uint* Bb = Bu + 2 * tx;
    uint m[3][4], sc[3][2], hx[3][2], e[4], ec_cur[2], ec_nxt[2], tsc[2];
    hmin4p(Bb + (rb - 2) * BP2, m[0], tsc);
    hmin4p(Bb + (rb - 1) * BP2, m[1], tsc);
    hmin4p(Bb + (rb + 0) * BP2, m[2], sc[0]);
    erodep(m[0], m[1], m[2], (unsigned)(gy0 - 1) < (unsigned)H, eok, e);
    hmaxp(e, hx[0], ec_nxt);
    hmin4p(Bb + (rb + 1) * BP2, m[0], sc[1]);
    erodep(m[1], m[2], m[0], true, eok, e);
    hmaxp(e, hx[1], ec_cur);
#pragma unroll
    for (int k = 0; k < 4; k++) {
        hmin4p(Bb + (rb + 2 + k) * BP2, m[(k + 1) % 3], sc[(2 + k) % 3]);
        erodep(m[(k + 2) % 3], m[k % 3], m[(k + 1) % 3],
               (unsigned)(gy0 + k + 1) < (unsigned)H, eok, e);
        hmaxp(e, hx[(k + 2) % 3], ec_nxt);
        uint t0 = pmax(hx[k % 3][0], pmax(hx[(k + 1) % 3][0], hx[(k + 2) % 3][0]));
        uint t1 = pmax(hx[k % 3][1], pmax(hx[(k + 1) % 3][1], hx[(k + 2) % 3][1]));
        uint o0 = upd_pair(sc[k % 3][0], ec_cur[0], t0);
        uint o1 = upd_pair(sc[k % 3][1], ec_cur[1], t1);
        if (TOREG) {
            h2 a = __builtin_bit_cast(h2, o0);
            h2 b = __builtin_bit_cast(h2, o1);
            oreg[k][0] = (float)a.x; oreg[k][1] = (float)a.y;
            oreg[k][2] = (float)b.x; oreg[k][3] = (float)b.y;
        } else {
            *(uint2*)(gdst + (size_t)(gy0 + k) * W + X) = make_uint2(o0, o1);
        }
        ec_cur[0] = ec_nxt[0]; ec_cur[1] = ec_nxt[1];
    }
}

// ---- K1: sigmoid + dice partials (fused in fillA) + iters 1,2 ----
__global__ __launch_bounds__(256, 6) void k_first(
    const float* __restrict__ logits, const float* __restrict__ target,
    f16* __restrict__ outb, float* __restrict__ parts0, float* __restrict__ parts1) {
    __shared__ __align__(16) uint A[AROWS * APU];
    __shared__ __align__(16) uint Bu[BROWS * BP2];
    __shared__ float red[8];
    const int img = blockIdx.z;
    const int tileX = blockIdx.x * 64, tileY = blockIdx.y * 64;
    const int tid = threadIdx.y * 16 + threadIdx.x;
    const bool pred = (img < NPRED);
    float2 ab;
    if (pred) ab = fillA_f32p<1>(A, logits + (size_t)img * IMG,
                                 target + (size_t)img * IMG, tileX, tileY, tid);
    else      ab = fillA_f32p<0>(A, target + (size_t)(img - NPRED) * IMG,
                                 nullptr, tileX, tileY, tid);
    __syncthreads();
    float a = wsum64(ab.x), b = wsum64(ab.y);
    if ((tid & 63) == 0) { red[tid >> 6] = a; red[4 + (tid >> 6)] = b; }
    stage1(A, Bu, tileX, tileY, tid);
    __syncthreads();
    if (tid == 0) {
        int bi = blockIdx.z * 64 + blockIdx.y * 8 + blockIdx.x;
        parts0[bi] = red[0] + red[1] + red[2] + red[3];
        parts1[bi] = red[4] + red[5] + red[6] + red[7];
    }
    stage2<false>(Bu, tileX, tileY, threadIdx.x, threadIdx.y,
                  outb + (size_t)img * IMG, nullptr);
}

// ---- K2..K4: two iterations, fp16 buf -> fp16 buf ----
__global__ __launch_bounds__(256, 6) void k_mid(
    const f16* __restrict__ in, f16* __restrict__ outb) {
    __shared__ __align__(16) uint A[AROWS * APU];
    __shared__ __align__(16) uint Bu[BROWS * BP2];
    const int img = blockIdx.z;
    const int tileX = blockIdx.x * 64, tileY = blockIdx.y * 64;
    const int tid = threadIdx.y * 16 + threadIdx.x;
    fillA_f16p(A, in + (size_t)img * IMG, tileX, tileY, tid);
    __syncthreads();
    stage1(A, Bu, tileX, tileY, tid);
    __syncthreads();
    stage2<false>(Bu, tileX, tileY, threadIdx.x, threadIdx.y,
                  outb + (size_t)img * IMG, nullptr);
}

// ---- K5: iters 9,10 for pred tile AND matching target tile; skel-dice partials ----
__global__ __launch_bounds__(256, 6) void k_last(
    const f16* __restrict__ in, float* __restrict__ pA,
    float* __restrict__ pB, float* __restrict__ pC) {
    __shared__ __align__(16) uint A[AROWS * APU];
    __shared__ __align__(16) uint Bu[BROWS * BP2];
    __shared__ float red[12];
    const int img = blockIdx.z;                  // 0..31
    const int tileX = blockIdx.x * 64, tileY = blockIdx.y * 64;
    const int tid = threadIdx.y * 16 + threadIdx.x;
    float op[4][4], ot[4][4];
    fillA_f16p(A, in + (size_t)img * IMG, tileX, tileY, tid);
    __syncthreads();
    stage1(A, Bu, tileX, tileY, tid);
    __syncthreads();
    stage2<true>(Bu, tileX, tileY, threadIdx.x, threadIdx.y, nullptr, op);
    fillA_f16p(A, in + (size_t)(img + NPRED) * IMG, tileX, tileY, tid);
    __syncthreads();   // all threads past stage2 B-reads before stage1 rewrites B
    stage1(A, Bu, tileX, tileY, tid);
    __syncthreads();
    stage2<true>(Bu, tileX, tileY, threadIdx.x, threadIdx.y, nullptr, ot);
    float a = 0.0f, b = 0.0f, c = 0.0f;
#pragma unroll
    for (int k = 0; k < 4; k++)
#pragma unroll
        for (int j = 0; j < 4; j++) {
            a += op[k][j] * ot[k][j];
            b += op[k][j];
            c += ot[k][j];
        }
    a = wsum64(a); b = wsum64(b); c = wsum64(c);
    if ((tid & 63) == 0) {
        red[tid >> 6] = a; red[4 + (tid >> 6)] = b; red[8 + (tid >> 6)] = c;
    }
    __syncthreads();
    if (tid == 0) {
        int bi = img * 64 + blockIdx.y * 8 + blockIdx.x;
        pA[bi] = red[0] + red[1] + red[2] + red[3];
        pB[bi] = red[4] + red[5] + red[6] + red[7];
        pC[bi] = red[8] + red[9] + red[10] + red[11];
    }
}

// ---- per-image dice from 64 tile partials (1 wave per image) ----
__global__ __launch_bounds__(64) void finalize_img(
    const float* __restrict__ parts0, const float* __restrict__ parts1,
    const float* __restrict__ pA, const float* __restrict__ pB,
    const float* __restrict__ pC, float* __restrict__ dices) {
    const int i = blockIdx.x, t = threadIdx.x;
    float inter = wsum64(parts0[i * 64 + t]);
    float sp = wsum64(parts1[i * 64 + t]);
    float st = wsum64(parts0[(NPRED + i) * 64 + t]);
    float i2 = wsum64(pA[i * 64 + t]);
    float sp2 = wsum64(pB[i * 64 + t]);
    float st2 = wsum64(pC[i * 64 + t]);
    if (t == 0) {
        dices[i] = (float)((2.0 * (double)inter + 1e-5) / ((double)sp + (double)st + 1e-5));
        dices[32 + i] = (float)((2.0 * (double)i2 + 1e-5) / ((double)sp2 + (double)st2 + 1e-5));
    }
}

__global__ void finalize_out(const float* __restrict__ dices, float* __restrict__ out) {
    const int t = threadIdx.x;
    double d = 0.0, sd = 0.0;
    if (t < 32) { d = dices[t]; sd = dices[32 + t]; }
#pragma unroll
    for (int o = 32; o > 0; o >>= 1) { d += __shfl_down(d, o); sd += __shfl_down(sd, o); }
    if (t == 0) {
        d *= (1.0 / 32.0); sd *= (1.0 / 32.0);
        out[0] = (float)(0.5 * (1.0 - d) + 0.5 * (1.0 - sd));
        out[1] = (float)d;
        out[2] = (float)sd;
    }
}

extern "C" void kernel_launch(void* const* d_in, const int* in_sizes, int n_in,
                              void* d_out, int out_size, void* d_ws, size_t ws_size,
                              hipStream_t stream) {
    (void)in_sizes; (void)n_in; (void)out_size; (void)ws_size;
    const float* logits = (const float*)d_in[0];
    const float* target = (const float*)d_in[1];
    float* out = (float*)d_out;
    f16* buf0 = (f16*)d_ws;                         // 64*262144 halves (33.5 MB)
    f16* buf1 = buf0 + (size_t)NIMG * IMG;
    float* parts0 = (float*)(buf1 + (size_t)NIMG * IMG);   // 4096
    float* parts1 = parts0 + 4096;                  // 4096
    float* pA = parts1 + 4096;                      // 2048
    float* pB = pA + 2048;
    float* pC = pB + 2048;
    float* dices = pC + 2048;                       // 64

    dim3 blk(16, 16, 1);
    k_first<<<dim3(8, 8, NIMG), blk, 0, stream>>>(logits, target, buf0, parts0, parts1);
    k_mid<<<dim3(8, 8, NIMG), blk, 0, stream>>>(buf0, buf1);   // iters 3,4
    k_mid<<<dim3(8, 8, NIMG), blk, 0, stream>>>(buf1, buf0);   // iters 5,6
    k_mid<<<dim3(8, 8, NIMG), blk, 0, stream>>>(buf0, buf1);   // iters 7,8
    k_last<<<dim3(8, 8, NPRED), blk, 0, stream>>>(buf1, pA, pB, pC);  // iters 9,10 + partials
    finalize_img<<<32, 64, 0, stream>>>(parts0, parts1, pA, pB, pC, dices);
    finalize_out<<<1, 64, 0, stream>>>(dices, out);
}

// Round 2
// 227.586 us; speedup vs baseline: 1.1671x; 1.1671x over previous
//
#include <hip/hip_runtime.h>
#include <hip/hip_fp16.h>
#include <math.h>

// clDice loss on 32x1x512x512: sigmoid + dice + 10x soft-skeletonize + skel dice.
// R1: per-block partials (1059 -> 466 us). R3: fused 2 iters/kernel via LDS (485).
// R5: 256 thr/block (316). R7: fp16 ping-pong + fp16 LDS B (262).
// R9: packed fp16 stencil (v_pk_min/max) - instrs down, dur flat (265): issue
//     efficiency pinned ~60%, so only instr COUNT moves dur.
// R10: 8-px work quantum + 64x128 tile:
//     - hmin/hmax share interior ops across 8 cols: ~78 VALU / 8 px vs 96 (w=4);
//     - 2x ds_read_b128 per stencil row (LDS ops/px -60%);
//     - stage1 238 items, stage2 256 items @ 256 threads (full util);
//     - template<EDGE>: interior blocks (37.5%) run with ZERO bounds masks;
//     - uint4 fill (16B/lane). LDS 39.9KB -> 4 blocks/CU (16 waves).

#define H 512
#define W 512
#define IMG (H * W)
#define NIMG 64
#define NPRED 32

#define APU 72      // A row pitch in uints (2 fp16/uint); uint u <-> tile cols (2u-8,2u-7)
#define AROWS 74    // row r <-> gy = tileY + r - 4; data rows 0..71 (72,73 pad)
#define BPU 68      // B row pitch in uints; uint u <-> tile cols (2u-4,2u-3)
#define BROWS 68    // row br <-> gy = tileY + br - 2
#define TQ 17       // stage1 col-groups (8 px each): output cols 8g-4..8g+3
#define S1ITEMS 238 // 14 strips x 17 groups
#define FILLN (AROWS * 18)  // 74 rows x 18 uint4-slots

#define PINF2 0x7C007C00u   // +inf,+inf (erosion-neutral pad)
#define NINF2 0xFC00FC00u   // -inf,-inf (dilation-neutral mask)
#define ONE2  0x3C003C00u   // 1.0,1.0

typedef _Float16 f16;
typedef _Float16 h2 __attribute__((ext_vector_type(2)));
typedef __fp16 fp16v2 __attribute__((ext_vector_type(2)));

__device__ __forceinline__ float2 unpack2(uint u) {
    fp16v2 h = __builtin_bit_cast(fp16v2, u);
    return make_float2((float)h.x, (float)h.y);
}
__device__ __forceinline__ uint pack2(float a, float b) {
    fp16v2 h = __builtin_amdgcn_cvt_pkrtz(a, b);
    return __builtin_bit_cast(uint, h);
}
__device__ __forceinline__ uint pmin(uint a, uint b) {
    uint d; asm("v_pk_min_f16 %0, %1, %2" : "=v"(d) : "v"(a), "v"(b)); return d;
}
__device__ __forceinline__ uint pmax(uint a, uint b) {
    uint d; asm("v_pk_max_f16 %0, %1, %2" : "=v"(d) : "v"(a), "v"(b)); return d;
}
// (hi<<16)|(lo>>16): odd-aligned fp16 pair from two even-aligned pairs
__device__ __forceinline__ uint abit(uint hi, uint lo) {
    return __builtin_amdgcn_alignbit(hi, lo, 16);
}

__device__ __forceinline__ float wsum64(float v) {
#pragma unroll
    for (int o = 32; o > 0; o >>= 1) v += __shfl_down(v, o);
    return v;
}

// Horizontal 3-min at 6 aligned pairs (cols c0-2..c0+9) from 8 uints (cols
// c0-4..c0+11), where p points at the uint 2 pairs left of the first output
// pair. Two ds_read_b128. Also returns center pairs sc (cols c0..c0+7).
__device__ __forceinline__ void hmin8p(const uint* __restrict__ p, uint m[6], uint sc[4]) {
    uint4 w0 = *(const uint4*)(p);
    uint4 w1 = *(const uint4*)(p + 4);
    uint w[8] = {w0.x, w0.y, w0.z, w0.w, w1.x, w1.y, w1.z, w1.w};
    sc[0] = w[2]; sc[1] = w[3]; sc[2] = w[4]; sc[3] = w[5];
    uint s[7];
#pragma unroll
    for (int j = 0; j < 7; j++) s[j] = abit(w[j + 1], w[j]);
#pragma unroll
    for (int i = 0; i < 6; i++) m[i] = pmin(s[i], pmin(w[i + 1], s[i + 1]));
}

// Vertical 3-min; EDGE adds center-out-of-image mask (-inf). Pairs are
// even-aligned and image x-bounds (0,512) are even, so masks are pair-uniform.
template<bool EDGE>
__device__ __forceinline__ void erode8(const uint a[6], const uint b[6], const uint c[6],
                                       bool rowok, const bool* eok, uint e[6]) {
#pragma unroll
    for (int i = 0; i < 6; i++) {
        uint v = pmin(a[i], pmin(b[i], c[i]));
        e[i] = EDGE ? ((rowok && eok[i]) ? v : NINF2) : v;
    }
}

// Horizontal 3-max at the 4 center pairs; ec = eroded center pairs.
__device__ __forceinline__ void hmax8(const uint e[6], uint hx[4], uint ec[4]) {
    uint a[5];
#pragma unroll
    for (int j = 0; j < 5; j++) a[j] = abit(e[j + 1], e[j]);
#pragma unroll
    for (int p = 0; p < 4; p++) {
        hx[p] = pmax(a[p], pmax(e[p + 1], a[p + 1]));
        ec[p] = e[p + 1];
    }
}

// skel update, packed fp16: o = clamp(s - (s-e)*t, 0, 1).
__device__ __forceinline__ uint upd_pair(uint s, uint ec, uint t) {
    h2 sh = __builtin_bit_cast(h2, s);
    h2 eh = __builtin_bit_cast(h2, ec);
    h2 th = __builtin_bit_cast(h2, t);
    h2 o = sh - (sh - eh) * th;           // v_pk_add + v_pk_fma
    return pmin(pmax(__builtin_bit_cast(uint, o), 0u), ONE2);
}

// Fill packed-fp16 LDS A from fp32 source (optional sigmoid); fuse dice
// partials over the 64x128 interior (fp32 pre-pack values -> exact dice).
template<bool EDGE, int SIG>
__device__ float2 fillA_f32(uint* __restrict__ A, const float* __restrict__ src,
                            const float* __restrict__ tgt,
                            int tileX, int tileY, int tid) {
    float a = 0.0f, b = 0.0f;
    for (int i = tid; i < FILLN; i += 256) {
        const int r = i / 18;
        const int q = i - 18 * r;
        const int gy = tileY + r - 4;
        const int gx = tileX - 8 + 8 * q;
        uint4 v = make_uint4(PINF2, PINF2, PINF2, PINF2);
        const bool ok = EDGE ? (r < 72 && (unsigned)gy < (unsigned)H &&
                                (unsigned)gx < (unsigned)W)
                             : true;
        if (ok) {
            const float* sp = src + (size_t)gy * W + gx;
            float4 f0 = *(const float4*)(sp);
            float4 f1 = *(const float4*)(sp + 4);
            if (SIG) {
                f0.x = 1.0f / (1.0f + __expf(-f0.x));
                f0.y = 1.0f / (1.0f + __expf(-f0.y));
                f0.z = 1.0f / (1.0f + __expf(-f0.z));
                f0.w = 1.0f / (1.0f + __expf(-f0.w));
                f1.x = 1.0f / (1.0f + __expf(-f1.x));
                f1.y = 1.0f / (1.0f + __expf(-f1.y));
                f1.z = 1.0f / (1.0f + __expf(-f1.z));
                f1.w = 1.0f / (1.0f + __expf(-f1.w));
            }
            if (((unsigned)(r - 4) < 64u) && ((unsigned)(q - 1) < 16u)) {
                if (SIG) {
                    const float* tp = tgt + (size_t)gy * W + gx;
                    float4 t0 = *(const float4*)(tp);
                    float4 t1 = *(const float4*)(tp + 4);
                    a += f0.x * t0.x + f0.y * t0.y + f0.z * t0.z + f0.w * t0.w
                       + f1.x * t1.x + f1.y * t1.y + f1.z * t1.z + f1.w * t1.w;
                    b += f0.x + f0.y + f0.z + f0.w + f1.x + f1.y + f1.z + f1.w;
                } else {
                    a += f0.x + f0.y + f0.z + f0.w + f1.x + f1.y + f1.z + f1.w;
                }
            }
            v.x = pack2(f0.x, f0.y); v.y = pack2(f0.z, f0.w);
            v.z = pack2(f1.x, f1.y); v.w = pack2(f1.z, f1.w);
        }
        *(uint4*)(A + r * APU + 4 * q) = v;
    }
    return make_float2(a, b);
}

template<bool EDGE>
__device__ void fillA_f16(uint* __restrict__ A, const f16* __restrict__ src,
                          int tileX, int tileY, int tid) {
    for (int i = tid; i < FILLN; i += 256) {
        const int r = i / 18;
        const int q = i - 18 * r;
        const int gy = tileY + r - 4;
        const int gx = tileX - 8 + 8 * q;
        uint4 v;
        if (EDGE) {
            v = make_uint4(PINF2, PINF2, PINF2, PINF2);
            if (r < 72 && (unsigned)gy < (unsigned)H && (unsigned)gx < (unsigned)W)
                v = *(const uint4*)(src + (size_t)gy * W + gx);
        } else {
            v = *(const uint4*)(src + (size_t)gy * W + gx);
        }
        *(uint4*)(A + r * APU + 4 * q) = v;
    }
}

// Stage 1: one skeletonize iteration A(fp16) -> B(fp16). 238 items =
// 14 strips(5 rows) x 17 groups(8 cols); rolling 3-row window.
template<bool EDGE>
__device__ void stage1(const uint* __restrict__ Au, uint* __restrict__ Bu,
                       int tileX, int tileY, int tid) {
    if (tid >= S1ITEMS) return;
    const int s = tid / TQ;
    const int g = tid - TQ * s;
    const int gcb = tileX + 8 * g - 4;   // global col of first output
    const int ys = tileY - 2 + 5 * s;    // global row of first output
    bool eok[6], wok[4];
    if (EDGE) {
#pragma unroll
        for (int i = 0; i < 6; i++) eok[i] = ((unsigned)(gcb - 2 + 2 * i) < (unsigned)W);
#pragma unroll
        for (int p = 0; p < 4; p++) wok[p] = ((unsigned)(gcb + 2 * p) < (unsigned)W);
    }
    const int lr = 5 * s + 2;
    const uint* Ab = Au + 4 * g;
    uint m[3][6], sc[3][4], hx[3][4], e[6], ec_cur[4], ec_nxt[4], tsc[4];
    hmin8p(Ab + (lr - 2) * APU, m[0], tsc);
    hmin8p(Ab + (lr - 1) * APU, m[1], tsc);
    hmin8p(Ab + (lr + 0) * APU, m[2], sc[0]);
    erode8<EDGE>(m[0], m[1], m[2], (unsigned)(ys - 1) < (unsigned)H, eok, e);
    hmax8(e, hx[0], ec_nxt);
    hmin8p(Ab + (lr + 1) * APU, m[0], sc[1]);
    erode8<EDGE>(m[1], m[2], m[0], (unsigned)ys < (unsigned)H, eok, e);
    hmax8(e, hx[1], ec_cur);
#pragma unroll
    for (int k = 0; k < 5; k++) {
        hmin8p(Ab + (lr + 2 + k) * APU, m[(k + 1) % 3], sc[(2 + k) % 3]);
        erode8<EDGE>(m[(k + 2) % 3], m[k % 3], m[(k + 1) % 3],
                     (unsigned)(ys + k + 1) < (unsigned)H, eok, e);
        hmax8(e, hx[(k + 2) % 3], ec_nxt);
        const int br = 5 * s + k;
        if (br < BROWS) {
            const bool rin = EDGE ? ((unsigned)(ys + k) < (unsigned)H) : true;
            uint o[4];
#pragma unroll
            for (int p = 0; p < 4; p++) {
                uint t = pmax(hx[k % 3][p], pmax(hx[(k + 1) % 3][p], hx[(k + 2) % 3][p]));
                uint v = upd_pair(sc[k % 3][p], ec_cur[p], t);
                o[p] = EDGE ? ((rin && wok[p]) ? v : PINF2) : v;
            }
            *(uint4*)(Bu + br * BPU + 4 * g) = make_uint4(o[0], o[1], o[2], o[3]);
        }
#pragma unroll
        for (int p = 0; p < 4; p++) ec_cur[p] = ec_nxt[p];
    }
}

// Stage 2: second iteration B(fp16) -> interior 64x128 (fp16 global or regs).
// 256 items = 16 groups(8 cols) x 16 strips(4 rows).
template<bool EDGE, bool TOREG>
__device__ void stage2(const uint* __restrict__ Bu, int tileX, int tileY, int tid,
                       f16* __restrict__ gdst, uint* __restrict__ oreg) {
    const int g = tid & 15;
    const int ty = tid >> 4;
    const int X = tileX + 8 * g;
    const int gy0 = tileY + 4 * ty;
    const int rb = 4 * ty + 2;
    bool eok[6];
    if (EDGE) {
#pragma unroll
        for (int i = 0; i < 6; i++) eok[i] = ((unsigned)(X - 2 + 2 * i) < (unsigned)W);
    }
    const uint* Bb = Bu + 4 * g;
    uint m[3][6], sc[3][4], hx[3][4], e[6], ec_cur[4], ec_nxt[4], tsc[4];
    hmin8p(Bb + (rb - 2) * BPU, m[0], tsc);
    hmin8p(Bb + (rb - 1) * BPU, m[1], tsc);
    hmin8p(Bb + (rb + 0) * BPU, m[2], sc[0]);
    erode8<EDGE>(m[0], m[1], m[2], (unsigned)(gy0 - 1) < (unsigned)H, eok, e);
    hmax8(e, hx[0], ec_nxt);
    hmin8p(Bb + (rb + 1) * BPU, m[0], sc[1]);
    erode8<EDGE>(m[1], m[2], m[0], true, eok, e);
    hmax8(e, hx[1], ec_cur);
#pragma unroll
    for (int k = 0; k < 4; k++) {
        hmin8p(Bb + (rb + 2 + k) * BPU, m[(k + 1) % 3], sc[(2 + k) % 3]);
        erode8<EDGE>(m[(k + 2) % 3], m[k % 3], m[(k + 1) % 3],
                     (unsigned)(gy0 + k + 1) < (unsigned)H, eok, e);
        hmax8(e, hx[(k + 2) % 3], ec_nxt);
        uint o[4];
#pragma unroll
        for (int p = 0; p < 4; p++) {
            uint t = pmax(hx[k % 3][p], pmax(hx[(k + 1) % 3][p], hx[(k + 2) % 3][p]));
            o[p] = upd_pair(sc[k % 3][p], ec_cur[p], t);
        }
        if (TOREG) {
#pragma unroll
            for (int p = 0; p < 4; p++) oreg[4 * k + p] = o[p];
        } else {
            *(uint4*)(gdst + (size_t)(gy0 + k) * W + X) = make_uint4(o[0], o[1], o[2], o[3]);
        }
#pragma unroll
        for (int p = 0; p < 4; p++) ec_cur[p] = ec_nxt[p];
    }
}

__device__ __forceinline__ bool is_edge() {
    return (blockIdx.x == 0) | (blockIdx.x == 3) | (blockIdx.y == 0) | (blockIdx.y == 7);
}

// ---- K1: sigmoid + dice partials (fused in fill) + iters 1,2 ----
__global__ __launch_bounds__(256, 4) void k_first(
    const float* __restrict__ logits, const float* __restrict__ target,
    f16* __restrict__ outb, float* __restrict__ parts0, float* __restrict__ parts1) {
    __shared__ __align__(16) uint A[AROWS * APU];
    __shared__ __align__(16) uint Bu[BROWS * BPU];
    __shared__ float red[8];
    const int img = blockIdx.z;
    const int tileX = blockIdx.x * 128, tileY = blockIdx.y * 64;
    const int tid = threadIdx.x;
    const bool pred = (img < NPRED);
    const bool edge = is_edge();
    float2 ab;
    if (edge) {
        if (pred) ab = fillA_f32<true, 1>(A, logits + (size_t)img * IMG,
                                          target + (size_t)img * IMG, tileX, tileY, tid);
        else      ab = fillA_f32<true, 0>(A, target + (size_t)(img - NPRED) * IMG,
                                          nullptr, tileX, tileY, tid);
    } else {
        if (pred) ab = fillA_f32<false, 1>(A, logits + (size_t)img * IMG,
                                           target + (size_t)img * IMG, tileX, tileY, tid);
        else      ab = fillA_f32<false, 0>(A, target + (size_t)(img - NPRED) * IMG,
                                           nullptr, tileX, tileY, tid);
    }
    __syncthreads();
    float a = wsum64(ab.x), b = wsum64(ab.y);
    if ((tid & 63) == 0) { red[tid >> 6] = a; red[4 + (tid >> 6)] = b; }
    if (edge) stage1<true>(A, Bu, tileX, tileY, tid);
    else      stage1<false>(A, Bu, tileX, tileY, tid);
    __syncthreads();
    if (tid == 0) {
        int bi = blockIdx.z * 32 + blockIdx.y * 4 + blockIdx.x;
        parts0[bi] = red[0] + red[1] + red[2] + red[3];
        parts1[bi] = red[4] + red[5] + red[6] + red[7];
    }
    if (edge) stage2<true, false>(Bu, tileX, tileY, tid, outb + (size_t)img * IMG, nullptr);
    else      stage2<false, false>(Bu, tileX, tileY, tid, outb + (size_t)img * IMG, nullptr);
}

// ---- K2..K4: two iterations, fp16 buf -> fp16 buf ----
__global__ __launch_bounds__(256, 4) void k_mid(
    const f16* __restrict__ in, f16* __restrict__ outb) {
    __shared__ __align__(16) uint A[AROWS * APU];
    __shared__ __align__(16) uint Bu[BROWS * BPU];
    const int img = blockIdx.z;
    const int tileX = blockIdx.x * 128, tileY = blockIdx.y * 64;
    const int tid = threadIdx.x;
    const bool edge = is_edge();
    if (edge) {
        fillA_f16<true>(A, in + (size_t)img * IMG, tileX, tileY, tid);
        __syncthreads();
        stage1<true>(A, Bu, tileX, tileY, tid);
        __syncthreads();
        stage2<true, false>(Bu, tileX, tileY, tid, outb + (size_t)img * IMG, nullptr);
    } else {
        fillA_f16<false>(A, in + (size_t)img * IMG, tileX, tileY, tid);
        __syncthreads();
        stage1<false>(A, Bu, tileX, tileY, tid);
        __syncthreads();
        stage2<false, false>(Bu, tileX, tileY, tid, outb + (size_t)img * IMG, nullptr);
    }
}

// ---- K5: iters 9,10 for pred tile AND matching target tile; skel-dice partials ----
__global__ __launch_bounds__(256, 4) void k_last(
    const f16* __restrict__ in, float* __restrict__ pA,
    float* __restrict__ pB, float* __restrict__ pC) {
    __shared__ __align__(16) uint A[AROWS * APU];
    __shared__ __align__(16) uint Bu[BROWS * BPU];
    __shared__ float red[12];
    const int img = blockIdx.z;                  // 0..31
    const int tileX = blockIdx.x * 128, tileY = blockIdx.y * 64;
    const int tid = threadIdx.x;
    const bool edge = is_edge();
    uint op[16], ot[16];
    if (edge) {
        fillA_f16<true>(A, in + (size_t)img * IMG, tileX, tileY, tid);
        __syncthreads();
        stage1<true>(A, Bu, tileX, tileY, tid);
        __syncthreads();
        stage2<true, true>(Bu, tileX, tileY, tid, nullptr, op);
        fillA_f16<true>(A, in + (size_t)(img + NPRED) * IMG, tileX, tileY, tid);
        __syncthreads();   // all threads past stage2 B-reads before stage1 rewrites B
        stage1<true>(A, Bu, tileX, tileY, tid);
        __syncthreads();
        stage2<true, true>(Bu, tileX, tileY, tid, nullptr, ot);
    } else {
        fillA_f16<false>(A, in + (size_t)img * IMG, tileX, tileY, tid);
        __syncthreads();
        stage1<false>(A, Bu, tileX, tileY, tid);
        __syncthreads();
        stage2<false, true>(Bu, tileX, tileY, tid, nullptr, op);
        fillA_f16<false>(A, in + (size_t)(img + NPRED) * IMG, tileX, tileY, tid);
        __syncthreads();
        stage1<false>(A, Bu, tileX, tileY, tid);
        __syncthreads();
        stage2<false, true>(Bu, tileX, tileY, tid, nullptr, ot);
    }
    float a = 0.0f, b = 0.0f, c = 0.0f;
#pragma unroll
    for (int j = 0; j < 16; j++) {
        float2 p = unpack2(op[j]);
        float2 t = unpack2(ot[j]);
        a += p.x * t.x + p.y * t.y;
        b += p.x + p.y;
        c += t.x + t.y;
    }
    a = wsum64(a); b = wsum64(b); c = wsum64(c);
    if ((tid & 63) == 0) {
        red[tid >> 6] = a; red[4 + (tid >> 6)] = b; red[8 + (tid >> 6)] = c;
    }
    __syncthreads();
    if (tid == 0) {
        int bi = img * 32 + blockIdx.y * 4 + blockIdx.x;
        pA[bi] = red[0] + red[1] + red[2] + red[3];
        pB[bi] = red[4] + red[5] + red[6] + red[7];
        pC[bi] = red[8] + red[9] + red[10] + red[11];
    }
}

// ---- per-image dice from 32 tile partials (1 wave per image) ----
__global__ __launch_bounds__(64) void finalize_img(
    const float* __restrict__ parts0, const float* __restrict__ parts1,
    const float* __restrict__ pA, const float* __restrict__ pB,
    const float* __restrict__ pC, float* __restrict__ dices) {
    const int i = blockIdx.x, t = threadIdx.x;
    const bool v = (t < 32);
    float inter = wsum64(v ? parts0[i * 32 + t] : 0.0f);
    float sp = wsum64(v ? parts1[i * 32 + t] : 0.0f);
    float st = wsum64(v ? parts0[(NPRED + i) * 32 + t] : 0.0f);
    float i2 = wsum64(v ? pA[i * 32 + t] : 0.0f);
    float sp2 = wsum64(v ? pB[i * 32 + t] : 0.0f);
    float st2 = wsum64(v ? pC[i * 32 + t] : 0.0f);
    if (t == 0) {
        dices[i] = (float)((2.0 * (double)inter + 1e-5) / ((double)sp + (double)st + 1e-5));
        dices[32 + i] = (float)((2.0 * (double)i2 + 1e-5) / ((double)sp2 + (double)st2 + 1e-5));
    }
}

__global__ void finalize_out(const float* __restrict__ dices, float* __restrict__ out) {
    const int t = threadIdx.x;
    double d = 0.0, sd = 0.0;
    if (t < 32) { d = dices[t]; sd = dices[32 + t]; }
#pragma unroll
    for (int o = 32; o > 0; o >>= 1) { d += __shfl_down(d, o); sd += __shfl_down(sd, o); }
    if (t == 0) {
        d *= (1.0 / 32.0); sd *= (1.0 / 32.0);
        out[0] = (float)(0.5 * (1.0 - d) + 0.5 * (1.0 - sd));
        out[1] = (float)d;
        out[2] = (float)sd;
    }
}

extern "C" void kernel_launch(void* const* d_in, const int* in_sizes, int n_in,
                              void* d_out, int out_size, void* d_ws, size_t ws_size,
                              hipStream_t stream) {
    (void)in_sizes; (void)n_in; (void)out_size; (void)ws_size;
    const float* logits = (const float*)d_in[0];
    const float* target = (const float*)d_in[1];
    float* out = (float*)d_out;
    f16* buf0 = (f16*)d_ws;                         // 64*262144 halves (33.5 MB)
    f16* buf1 = buf0 + (size_t)NIMG * IMG;
    float* parts0 = (float*)(buf1 + (size_t)NIMG * IMG);   // 2048
    float* parts1 = parts0 + 2048;                  // 2048
    float* pA = parts1 + 2048;                      // 1024
    float* pB = pA + 1024;
    float* pC = pB + 1024;
    float* dices = pC + 1024;                       // 64

    dim3 blk(256, 1, 1);
    k_first<<<dim3(4, 8, NIMG), blk, 0, stream>>>(logits, target, buf0, parts0, parts1);
    k_mid<<<dim3(4, 8, NIMG), blk, 0, stream>>>(buf0, buf1);   // iters 3,4
    k_mid<<<dim3(4, 8, NIMG), blk, 0, stream>>>(buf1, buf0);   // iters 5,6
    k_mid<<<dim3(4, 8, NIMG), blk, 0, stream>>>(buf0, buf1);   // iters 7,8
    k_last<<<dim3(4, 8, NPRED), blk, 0, stream>>>(buf1, pA, pB, pC);  // iters 9,10 + partials
    finalize_img<<<32, 64, 0, stream>>>(parts0, parts1, pA, pB, pC, dices);
    finalize_out<<<1, 64, 0, stream>>>(dices, out);
}

// Round 3
// 219.975 us; speedup vs baseline: 1.2075x; 1.0346x over previous
//
#include <hip/hip_runtime.h>
#include <hip/hip_fp16.h>
#include <math.h>

// clDice loss on 32x1x512x512: sigmoid + dice + 10x soft-skeletonize + skel dice.
// R1: per-block partials (1059 -> 466 us). R3: fused 2 iters/kernel via LDS (485).
// R5: 256 thr/block (316). R7: fp16 ping-pong + fp16 LDS B (262).
// R9: packed fp16 stencil (v_pk_min/max), instrs down, dur flat (265).
// R10: 8-px quantum + 64x128 tile + EDGE templates (227); k_first regressed
//      (latency-bound at 4 blocks/CU: VALUBusy 59->33%).
// R11: attack latency, LDS unchanged:
//   - k_mid/k_last fill via global_load_lds DMA (LDS layout is exactly
//     base+16*i, lane-sequential -> wave-uniform dest constraint satisfied).
//     Boundary: clamped source addr (replicate pad is min-neutral for the
//     first erosion); fully-OOB x-columns ds_write +inf instead (they feed
//     in-image col 0/511 erosion; deeper halo is eok-masked don't-care).
//   - k_first fill batched 2x3 load-then-store: 6-12 loads in flight (MLP).

#define H 512
#define W 512
#define IMG (H * W)
#define NIMG 64
#define NPRED 32

#define APU 72      // A row pitch in uints (2 fp16/uint); uint u <-> tile cols (2u-8,2u-7)
#define AROWS 74    // row r <-> gy = tileY + r - 4; data rows 0..71 (72,73 pad)
#define BPU 68      // B row pitch in uints; uint u <-> tile cols (2u-4,2u-3)
#define BROWS 68    // row br <-> gy = tileY + br - 2
#define TQ 17       // stage1 col-groups (8 px each): output cols 8g-4..8g+3
#define S1ITEMS 238 // 14 strips x 17 groups
#define FILLN (AROWS * 18)  // 74 rows x 18 uint4-slots = 1332

#define PINF2 0x7C007C00u   // +inf,+inf (erosion-neutral pad)
#define NINF2 0xFC00FC00u   // -inf,-inf (dilation-neutral mask)
#define ONE2  0x3C003C00u   // 1.0,1.0

typedef _Float16 f16;
typedef _Float16 h2 __attribute__((ext_vector_type(2)));
typedef __fp16 fp16v2 __attribute__((ext_vector_type(2)));

__device__ __forceinline__ float2 unpack2(uint u) {
    fp16v2 h = __builtin_bit_cast(fp16v2, u);
    return make_float2((float)h.x, (float)h.y);
}
__device__ __forceinline__ uint pack2(float a, float b) {
    fp16v2 h = __builtin_amdgcn_cvt_pkrtz(a, b);
    return __builtin_bit_cast(uint, h);
}
__device__ __forceinline__ uint pmin(uint a, uint b) {
    uint d; asm("v_pk_min_f16 %0, %1, %2" : "=v"(d) : "v"(a), "v"(b)); return d;
}
__device__ __forceinline__ uint pmax(uint a, uint b) {
    uint d; asm("v_pk_max_f16 %0, %1, %2" : "=v"(d) : "v"(a), "v"(b)); return d;
}
// (hi<<16)|(lo>>16): odd-aligned fp16 pair from two even-aligned pairs
__device__ __forceinline__ uint abit(uint hi, uint lo) {
    return __builtin_amdgcn_alignbit(hi, lo, 16);
}

// async global->LDS DMA, 16B per lane. LDS dest must be wave-uniform base +
// lane*16, which our fill layout satisfies by construction.
__device__ __forceinline__ void lds_dma16(uint* l, const void* g) {
    __builtin_amdgcn_global_load_lds(
        (__attribute__((address_space(1))) void*)(g),
        (__attribute__((address_space(3))) void*)(l), 16, 0, 0);
}

__device__ __forceinline__ float wsum64(float v) {
#pragma unroll
    for (int o = 32; o > 0; o >>= 1) v += __shfl_down(v, o);
    return v;
}

// Horizontal 3-min at 6 aligned pairs (cols c0-2..c0+9) from 8 uints (cols
// c0-4..c0+11); p points at the uint 2 pairs left of the first output pair.
// Two ds_read_b128. Also returns center pairs sc (cols c0..c0+7).
__device__ __forceinline__ void hmin8p(const uint* __restrict__ p, uint m[6], uint sc[4]) {
    uint4 w0 = *(const uint4*)(p);
    uint4 w1 = *(const uint4*)(p + 4);
    uint w[8] = {w0.x, w0.y, w0.z, w0.w, w1.x, w1.y, w1.z, w1.w};
    sc[0] = w[2]; sc[1] = w[3]; sc[2] = w[4]; sc[3] = w[5];
    uint s[7];
#pragma unroll
    for (int j = 0; j < 7; j++) s[j] = abit(w[j + 1], w[j]);
#pragma unroll
    for (int i = 0; i < 6; i++) m[i] = pmin(s[i], pmin(w[i + 1], s[i + 1]));
}

// Vertical 3-min; EDGE adds center-out-of-image mask (-inf). Pairs are
// even-aligned and image x-bounds (0,512) are even, so masks are pair-uniform.
template<bool EDGE>
__device__ __forceinline__ void erode8(const uint a[6], const uint b[6], const uint c[6],
                                       bool rowok, const bool* eok, uint e[6]) {
#pragma unroll
    for (int i = 0; i < 6; i++) {
        uint v = pmin(a[i], pmin(b[i], c[i]));
        e[i] = EDGE ? ((rowok && eok[i]) ? v : NINF2) : v;
    }
}

// Horizontal 3-max at the 4 center pairs; ec = eroded center pairs.
__device__ __forceinline__ void hmax8(const uint e[6], uint hx[4], uint ec[4]) {
    uint a[5];
#pragma unroll
    for (int j = 0; j < 5; j++) a[j] = abit(e[j + 1], e[j]);
#pragma unroll
    for (int p = 0; p < 4; p++) {
        hx[p] = pmax(a[p], pmax(e[p + 1], a[p + 1]));
        ec[p] = e[p + 1];
    }
}

// skel update, packed fp16: o = clamp(s - (s-e)*t, 0, 1).
__device__ __forceinline__ uint upd_pair(uint s, uint ec, uint t) {
    h2 sh = __builtin_bit_cast(h2, s);
    h2 eh = __builtin_bit_cast(h2, ec);
    h2 th = __builtin_bit_cast(h2, t);
    h2 o = sh - (sh - eh) * th;           // v_pk_add + v_pk_fma
    return pmin(pmax(__builtin_bit_cast(uint, o), 0u), ONE2);
}

// Fill packed-fp16 LDS A from fp32 source (optional sigmoid); fuse dice
// partials over the 64x128 interior (fp32 pre-pack values -> exact dice).
// Batched 2 x 3: issue 3 items' loads (6-12 global loads) before consuming.
template<bool EDGE, int SIG>
__device__ float2 fillA_f32(uint* __restrict__ A, const float* __restrict__ src,
                            const float* __restrict__ tgt,
                            int tileX, int tileY, int tid) {
    float a = 0.0f, b = 0.0f;
#pragma unroll
    for (int hf = 0; hf < 2; hf++) {
        float4 v0[3], v1[3], t0[3], t1[3];
        bool ld[3];
#pragma unroll
        for (int j = 0; j < 3; j++) {
            const int i = tid + 256 * (3 * hf + j);
            const int r = i / 18;
            const int q = i - 18 * r;
            const int gy = tileY + r - 4;
            const int gx = tileX - 8 + 8 * q;
            bool ok = (i < FILLN);
            if (EDGE) ok = ok && (r < 72) && ((unsigned)gy < (unsigned)H) &&
                           ((unsigned)gx < (unsigned)W);
            ld[j] = ok;
            if (ok) {
                const float* sp = src + (size_t)gy * W + gx;
                v0[j] = *(const float4*)(sp);
                v1[j] = *(const float4*)(sp + 4);
                if (SIG) {
                    const float* tp = tgt + (size_t)gy * W + gx;
                    t0[j] = *(const float4*)(tp);
                    t1[j] = *(const float4*)(tp + 4);
                }
            }
        }
#pragma unroll
        for (int j = 0; j < 3; j++) {
            const int i = tid + 256 * (3 * hf + j);
            const int r = i / 18;
            const int q = i - 18 * r;
            if (i < FILLN) {
                uint4 w = make_uint4(PINF2, PINF2, PINF2, PINF2);
                if (ld[j]) {
                    float4 f0 = v0[j], f1 = v1[j];
                    if (SIG) {
                        f0.x = 1.0f / (1.0f + __expf(-f0.x));
                        f0.y = 1.0f / (1.0f + __expf(-f0.y));
                        f0.z = 1.0f / (1.0f + __expf(-f0.z));
                        f0.w = 1.0f / (1.0f + __expf(-f0.w));
                        f1.x = 1.0f / (1.0f + __expf(-f1.x));
                        f1.y = 1.0f / (1.0f + __expf(-f1.y));
                        f1.z = 1.0f / (1.0f + __expf(-f1.z));
                        f1.w = 1.0f / (1.0f + __expf(-f1.w));
                    }
                    if (((unsigned)(r - 4) < 64u) && ((unsigned)(q - 1) < 16u)) {
                        if (SIG) {
                            a += f0.x * t0[j].x + f0.y * t0[j].y + f0.z * t0[j].z +
                                 f0.w * t0[j].w + f1.x * t1[j].x + f1.y * t1[j].y +
                                 f1.z * t1[j].z + f1.w * t1[j].w;
                            b += f0.x + f0.y + f0.z + f0.w + f1.x + f1.y + f1.z + f1.w;
                        } else {
                            a += f0.x + f0.y + f0.z + f0.w + f1.x + f1.y + f1.z + f1.w;
                        }
                    }
                    w.x = pack2(f0.x, f0.y); w.y = pack2(f0.z, f0.w);
                    w.z = pack2(f1.x, f1.y); w.w = pack2(f1.z, f1.w);
                }
                *(uint4*)(A + r * APU + 4 * q) = w;
            }
        }
    }
    return make_float2(a, b);
}

// DMA fill from fp16 buffer. Source addresses clamped into the image
// (replicate padding: min/max-neutral for the first erosion; row halos
// correct, deeper halo don't-care). Fully-OOB x-column items (only at
// bx==0 / bx==3, 8-aligned so never straddling) write +inf directly --
// each LDS address has exactly one writer, so no DMA/ds_write race.
__device__ __forceinline__ void fill_dma(uint* __restrict__ A, const f16* __restrict__ src,
                                         int tileX, int tileY, int tid) {
#pragma unroll
    for (int j = 0; j < 6; j++) {
        const int i = tid + 256 * j;
        if (i < FILLN) {
            const int r = i / 18;
            const int q = i - 18 * r;
            const int gy = tileY + r - 4;
            const int gx = tileX - 8 + 8 * q;
            if (gx < 0 || gx >= W) {
                *(uint4*)(A + 4 * i) = make_uint4(PINF2, PINF2, PINF2, PINF2);
            } else {
                const int gyc = min(max(gy, 0), H - 1);
                lds_dma16(A + 4 * i, src + (size_t)gyc * W + gx);
            }
        }
    }
}

// Stage 1: one skeletonize iteration A(fp16) -> B(fp16). 238 items =
// 14 strips(5 rows) x 17 groups(8 cols); rolling 3-row window.
template<bool EDGE>
__device__ void stage1(const uint* __restrict__ Au, uint* __restrict__ Bu,
                       int tileX, int tileY, int tid) {
    if (tid >= S1ITEMS) return;
    const int s = tid / TQ;
    const int g = tid - TQ * s;
    const int gcb = tileX + 8 * g - 4;   // global col of first output
    const int ys = tileY - 2 + 5 * s;    // global row of first output
    bool eok[6], wok[4];
    if (EDGE) {
#pragma unroll
        for (int i = 0; i < 6; i++) eok[i] = ((unsigned)(gcb - 2 + 2 * i) < (unsigned)W);
#pragma unroll
        for (int p = 0; p < 4; p++) wok[p] = ((unsigned)(gcb + 2 * p) < (unsigned)W);
    }
    const int lr = 5 * s + 2;
    const uint* Ab = Au + 4 * g;
    uint m[3][6], sc[3][4], hx[3][4], e[6], ec_cur[4], ec_nxt[4], tsc[4];
    hmin8p(Ab + (lr - 2) * APU, m[0], tsc);
    hmin8p(Ab + (lr - 1) * APU, m[1], tsc);
    hmin8p(Ab + (lr + 0) * APU, m[2], sc[0]);
    erode8<EDGE>(m[0], m[1], m[2], (unsigned)(ys - 1) < (unsigned)H, eok, e);
    hmax8(e, hx[0], ec_nxt);
    hmin8p(Ab + (lr + 1) * APU, m[0], sc[1]);
    erode8<EDGE>(m[1], m[2], m[0], (unsigned)ys < (unsigned)H, eok, e);
    hmax8(e, hx[1], ec_cur);
#pragma unroll
    for (int k = 0; k < 5; k++) {
        hmin8p(Ab + (lr + 2 + k) * APU, m[(k + 1) % 3], sc[(2 + k) % 3]);
        erode8<EDGE>(m[(k + 2) % 3], m[k % 3], m[(k + 1) % 3],
                     (unsigned)(ys + k + 1) < (unsigned)H, eok, e);
        hmax8(e, hx[(k + 2) % 3], ec_nxt);
        const int br = 5 * s + k;
        if (br < BROWS) {
            const bool rin = EDGE ? ((unsigned)(ys + k) < (unsigned)H) : true;
            uint o[4];
#pragma unroll
            for (int p = 0; p < 4; p++) {
                uint t = pmax(hx[k % 3][p], pmax(hx[(k + 1) % 3][p], hx[(k + 2) % 3][p]));
                uint v = upd_pair(sc[k % 3][p], ec_cur[p], t);
                o[p] = EDGE ? ((rin && wok[p]) ? v : PINF2) : v;
            }
            *(uint4*)(Bu + br * BPU + 4 * g) = make_uint4(o[0], o[1], o[2], o[3]);
        }
#pragma unroll
        for (int p = 0; p < 4; p++) ec_cur[p] = ec_nxt[p];
    }
}

// Stage 2: second iteration B(fp16) -> interior 64x128 (fp16 global or regs).
// 256 items = 16 groups(8 cols) x 16 strips(4 rows).
template<bool EDGE, bool TOREG>
__device__ void stage2(const uint* __restrict__ Bu, int tileX, int tileY, int tid,
                       f16* __restrict__ gdst, uint* __restrict__ oreg) {
    const int g = tid & 15;
    const int ty = tid >> 4;
    const int X = tileX + 8 * g;
    const int gy0 = tileY + 4 * ty;
    const int rb = 4 * ty + 2;
    bool eok[6];
    if (EDGE) {
#pragma unroll
        for (int i = 0; i < 6; i++) eok[i] = ((unsigned)(X - 2 + 2 * i) < (unsigned)W);
    }
    const uint* Bb = Bu + 4 * g;
    uint m[3][6], sc[3][4], hx[3][4], e[6], ec_cur[4], ec_nxt[4], tsc[4];
    hmin8p(Bb + (rb - 2) * BPU, m[0], tsc);
    hmin8p(Bb + (rb - 1) * BPU, m[1], tsc);
    hmin8p(Bb + (rb + 0) * BPU, m[2], sc[0]);
    erode8<EDGE>(m[0], m[1], m[2], (unsigned)(gy0 - 1) < (unsigned)H, eok, e);
    hmax8(e, hx[0], ec_nxt);
    hmin8p(Bb + (rb + 1) * BPU, m[0], sc[1]);
    erode8<EDGE>(m[1], m[2], m[0], true, eok, e);
    hmax8(e, hx[1], ec_cur);
#pragma unroll
    for (int k = 0; k < 4; k++) {
        hmin8p(Bb + (rb + 2 + k) * BPU, m[(k + 1) % 3], sc[(2 + k) % 3]);
        erode8<EDGE>(m[(k + 2) % 3], m[k % 3], m[(k + 1) % 3],
                     (unsigned)(gy0 + k + 1) < (unsigned)H, eok, e);
        hmax8(e, hx[(k + 2) % 3], ec_nxt);
        uint o[4];
#pragma unroll
        for (int p = 0; p < 4; p++) {
            uint t = pmax(hx[k % 3][p], pmax(hx[(k + 1) % 3][p], hx[(k + 2) % 3][p]));
            o[p] = upd_pair(sc[k % 3][p], ec_cur[p], t);
        }
        if (TOREG) {
#pragma unroll
            for (int p = 0; p < 4; p++) oreg[4 * k + p] = o[p];
        } else {
            *(uint4*)(gdst + (size_t)(gy0 + k) * W + X) = make_uint4(o[0], o[1], o[2], o[3]);
        }
#pragma unroll
        for (int p = 0; p < 4; p++) ec_cur[p] = ec_nxt[p];
    }
}

__device__ __forceinline__ bool is_edge() {
    return (blockIdx.x == 0) | (blockIdx.x == 3) | (blockIdx.y == 0) | (blockIdx.y == 7);
}

// ---- K1: sigmoid + dice partials (fused in fill) + iters 1,2 ----
__global__ __launch_bounds__(256, 4) void k_first(
    const float* __restrict__ logits, const float* __restrict__ target,
    f16* __restrict__ outb, float* __restrict__ parts0, float* __restrict__ parts1) {
    __shared__ __align__(16) uint A[AROWS * APU];
    __shared__ __align__(16) uint Bu[BROWS * BPU];
    __shared__ float red[8];
    const int img = blockIdx.z;
    const int tileX = blockIdx.x * 128, tileY = blockIdx.y * 64;
    const int tid = threadIdx.x;
    const bool pred = (img < NPRED);
    const bool edge = is_edge();
    float2 ab;
    if (edge) {
        if (pred) ab = fillA_f32<true, 1>(A, logits + (size_t)img * IMG,
                                          target + (size_t)img * IMG, tileX, tileY, tid);
        else      ab = fillA_f32<true, 0>(A, target + (size_t)(img - NPRED) * IMG,
                                          nullptr, tileX, tileY, tid);
    } else {
        if (pred) ab = fillA_f32<false, 1>(A, logits + (size_t)img * IMG,
                                           target + (size_t)img * IMG, tileX, tileY, tid);
        else      ab = fillA_f32<false, 0>(A, target + (size_t)(img - NPRED) * IMG,
                                           nullptr, tileX, tileY, tid);
    }
    __syncthreads();
    float a = wsum64(ab.x), b = wsum64(ab.y);
    if ((tid & 63) == 0) { red[tid >> 6] = a; red[4 + (tid >> 6)] = b; }
    if (edge) stage1<true>(A, Bu, tileX, tileY, tid);
    else      stage1<false>(A, Bu, tileX, tileY, tid);
    __syncthreads();
    if (tid == 0) {
        int bi = blockIdx.z * 32 + blockIdx.y * 4 + blockIdx.x;
        parts0[bi] = red[0] + red[1] + red[2] + red[3];
        parts1[bi] = red[4] + red[5] + red[6] + red[7];
    }
    if (edge) stage2<true, false>(Bu, tileX, tileY, tid, outb + (size_t)img * IMG, nullptr);
    else      stage2<false, false>(Bu, tileX, tileY, tid, outb + (size_t)img * IMG, nullptr);
}

// ---- K2..K4: two iterations, fp16 buf -> fp16 buf (DMA fill) ----
__global__ __launch_bounds__(256, 4) void k_mid(
    const f16* __restrict__ in, f16* __restrict__ outb) {
    __shared__ __align__(16) uint A[AROWS * APU];
    __shared__ __align__(16) uint Bu[BROWS * BPU];
    const int img = blockIdx.z;
    const int tileX = blockIdx.x * 128, tileY = blockIdx.y * 64;
    const int tid = threadIdx.x;
    const bool edge = is_edge();
    fill_dma(A, in + (size_t)img * IMG, tileX, tileY, tid);
    __syncthreads();
    if (edge) {
        stage1<true>(A, Bu, tileX, tileY, tid);
        __syncthreads();
        stage2<true, false>(Bu, tileX, tileY, tid, outb + (size_t)img * IMG, nullptr);
    } else {
        stage1<false>(A, Bu, tileX, tileY, tid);
        __syncthreads();
        stage2<false, false>(Bu, tileX, tileY, tid, outb + (size_t)img * IMG, nullptr);
    }
}

// ---- K5: iters 9,10 for pred tile AND matching target tile; skel-dice partials ----
__global__ __launch_bounds__(256, 4) void k_last(
    const f16* __restrict__ in, float* __restrict__ pA,
    float* __restrict__ pB, float* __restrict__ pC) {
    __shared__ __align__(16) uint A[AROWS * APU];
    __shared__ __align__(16) uint Bu[BROWS * BPU];
    __shared__ float red[12];
    const int img = blockIdx.z;                  // 0..31
    const int tileX = blockIdx.x * 128, tileY = blockIdx.y * 64;
    const int tid = threadIdx.x;
    const bool edge = is_edge();
    uint op[16], ot[16];
    fill_dma(A, in + (size_t)img * IMG, tileX, tileY, tid);
    __syncthreads();
    if (edge) {
        stage1<true>(A, Bu, tileX, tileY, tid);
        __syncthreads();
        stage2<true, true>(Bu, tileX, tileY, tid, nullptr, op);
        fill_dma(A, in + (size_t)(img + NPRED) * IMG, tileX, tileY, tid);
        __syncthreads();   // all threads past stage2 B-reads before stage1 rewrites B
        stage1<true>(A, Bu, tileX, tileY, tid);
        __syncthreads();
        stage2<true, true>(Bu, tileX, tileY, tid, nullptr, ot);
    } else {
        stage1<false>(A, Bu, tileX, tileY, tid);
        __syncthreads();
        stage2<false, true>(Bu, tileX, tileY, tid, nullptr, op);
        fill_dma(A, in + (size_t)(img + NPRED) * IMG, tileX, tileY, tid);
        __syncthreads();
        stage1<false>(A, Bu, tileX, tileY, tid);
        __syncthreads();
        stage2<false, true>(Bu, tileX, tileY, tid, nullptr, ot);
    }
    float a = 0.0f, b = 0.0f, c = 0.0f;
#pragma unroll
    for (int j = 0; j < 16; j++) {
        float2 p = unpack2(op[j]);
        float2 t = unpack2(ot[j]);
        a += p.x * t.x + p.y * t.y;
        b += p.x + p.y;
        c += t.x + t.y;
    }
    a = wsum64(a); b = wsum64(b); c = wsum64(c);
    if ((tid & 63) == 0) {
        red[tid >> 6] = a; red[4 + (tid >> 6)] = b; red[8 + (tid >> 6)] = c;
    }
    __syncthreads();
    if (tid == 0) {
        int bi = img * 32 + blockIdx.y * 4 + blockIdx.x;
        pA[bi] = red[0] + red[1] + red[2] + red[3];
        pB[bi] = red[4] + red[5] + red[6] + red[7];
        pC[bi] = red[8] + red[9] + red[10] + red[11];
    }
}

// ---- per-image dice from 32 tile partials (1 wave per image) ----
__global__ __launch_bounds__(64) void finalize_img(
    const float* __restrict__ parts0, const float* __restrict__ parts1,
    const float* __restrict__ pA, const float* __restrict__ pB,
    const float* __restrict__ pC, float* __restrict__ dices) {
    const int i = blockIdx.x, t = threadIdx.x;
    const bool v = (t < 32);
    float inter = wsum64(v ? parts0[i * 32 + t] : 0.0f);
    float sp = wsum64(v ? parts1[i * 32 + t] : 0.0f);
    float st = wsum64(v ? parts0[(NPRED + i) * 32 + t] : 0.0f);
    float i2 = wsum64(v ? pA[i * 32 + t] : 0.0f);
    float sp2 = wsum64(v ? pB[i * 32 + t] : 0.0f);
    float st2 = wsum64(v ? pC[i * 32 + t] : 0.0f);
    if (t == 0) {
        dices[i] = (float)((2.0 * (double)inter + 1e-5) / ((double)sp + (double)st + 1e-5));
        dices[32 + i] = (float)((2.0 * (double)i2 + 1e-5) / ((double)sp2 + (double)st2 + 1e-5));
    }
}

__global__ void finalize_out(const float* __restrict__ dices, float* __restrict__ out) {
    const int t = threadIdx.x;
    double d = 0.0, sd = 0.0;
    if (t < 32) { d = dices[t]; sd = dices[32 + t]; }
#pragma unroll
    for (int o = 32; o > 0; o >>= 1) { d += __shfl_down(d, o); sd += __shfl_down(sd, o); }
    if (t == 0) {
        d *= (1.0 / 32.0); sd *= (1.0 / 32.0);
        out[0] = (float)(0.5 * (1.0 - d) + 0.5 * (1.0 - sd));
        out[1] = (float)d;
        out[2] = (float)sd;
    }
}

extern "C" void kernel_launch(void* const* d_in, const int* in_sizes, int n_in,
                              void* d_out, int out_size, void* d_ws, size_t ws_size,
                              hipStream_t stream) {
    (void)in_sizes; (void)n_in; (void)out_size; (void)ws_size;
    const float* logits = (const float*)d_in[0];
    const float* target = (const float*)d_in[1];
    float* out = (float*)d_out;
    f16* buf0 = (f16*)d_ws;                         // 64*262144 halves (33.5 MB)
    f16* buf1 = buf0 + (size_t)NIMG * IMG;
    float* parts0 = (float*)(buf1 + (size_t)NIMG * IMG);   // 2048
    float* parts1 = parts0 + 2048;                  // 2048
    float* pA = parts1 + 2048;                      // 1024
    float* pB = pA + 1024;
    float* pC = pB + 1024;
    float* dices = pC + 1024;                       // 64

    dim3 blk(256, 1, 1);
    k_first<<<dim3(4, 8, NIMG), blk, 0, stream>>>(logits, target, buf0, parts0, parts1);
    k_mid<<<dim3(4, 8, NIMG), blk, 0, stream>>>(buf0, buf1);   // iters 3,4
    k_mid<<<dim3(4, 8, NIMG), blk, 0, stream>>>(buf1, buf0);   // iters 5,6
    k_mid<<<dim3(4, 8, NIMG), blk, 0, stream>>>(buf0, buf1);   // iters 7,8
    k_last<<<dim3(4, 8, NPRED), blk, 0, stream>>>(buf1, pA, pB, pC);  // iters 9,10 + partials
    finalize_img<<<32, 64, 0, stream>>>(parts0, parts1, pA, pB, pC, dices);
    finalize_out<<<1, 64, 0, stream>>>(dices, out);
}